// Round 11
// baseline (250.166 us; speedup 1.0000x reference)
//
#include <hip/hip_runtime.h>
#include <math.h>

// Problem constants (fixed by setup_inputs)
constexpr int B_ = 8;
constexpr int N_ = 16384;
constexpr int M_ = 1024;
constexpr int C_ = 256;
constexpr int NCHUNK = 8;
constexpr int CHUNK = M_ / NCHUNK;  // 128
constexpr int KEEP = 4;             // per-chunk survivors
constexpr int TOPK_BLOCK = 1024;    // 16 waves/block -> 2 blocks/CU -> 2 K$ streams

// DIAGNOSTIC ROUND (R11): amplification, third fix.
//  R8: "memory" clobber kept stores live but const+restrict let the PURE
//      COMPUTE be CSE'd across reps (+0.8us = 4 extra store passes).
//  R10: "+s" laundering defeated CSE, but same-address stores were DSE'd
//      -> upstream compute DCE'd (+0.6us = loop scaffolding).
//  R11: BOTH defenses: "+s" laundering (un-CSE-able loads) AND a per-rep
//      asm "v" VALUE SINK on the accumulators (rule-17 liveness; defeats
//      DSE/DCE), store once after the loop -> output byte-identical.
// topk x5, gather x3 (read side x3, write x1):
//   dur = base + 4*T_topk + 2*T_gread; amplified dispatches surface in
//   the rocprof top-5 (> ~80us fills) with their own counters.
constexpr int TOPK_REPS = 5;
constexpr int GATHER_REPS = 3;

// native 4-float vector for __builtin_nontemporal_store (HIP's float4 is a
// class type the builtin rejects; ext_vector_type is accepted).
typedef float nfloat4 __attribute__((ext_vector_type(4)));

// 4-deep sorted-insert network on POSITIVE floats (P0<=P1<=P2<=P3 invariant).
#define INSERT4(P, u)                                              \
  {                                                                \
    const float o0 = P##0, o1 = P##1, o2 = P##2;                   \
    P##0 = fminf(o0, (u));                                         \
    P##1 = __builtin_amdgcn_fmed3f(o0, P##1, (u));                 \
    P##2 = __builtin_amdgcn_fmed3f(o1, P##2, (u));                 \
    P##3 = __builtin_amdgcn_fmed3f(o2, P##3, (u));                 \
  }

// ---------------------------------------------------------------------------
// Kernel 0 (fused prep): blocks [0,32) pack centroids; blocks [32, 32+2048)
// transpose centroid_f [B,C,M] -> fT [B,M,C] via 32x32 LDS tiles (+1 pad).
// ---------------------------------------------------------------------------
__global__ __launch_bounds__(256) void prep_kernel(
    const float* __restrict__ cxyz,  // [B, M, 3]
    const float* __restrict__ cf,    // [B, C, M]
    float* __restrict__ csoa,        // [B][NCHUNK][CHUNK/2][8]
    float4* __restrict__ cpack,      // [B*M]
    float* __restrict__ fT)          // [B, M, C]
{
  __shared__ float tile[32][33];
  const int tx = threadIdx.x;  // 0..31
  const int ty = threadIdx.y;  // 0..7
  if (blockIdx.x < 32) {
    // ---- pack role ----
    const int i = blockIdx.x * 256 + (ty * 32 + tx);  // global centroid id
    if (i < B_ * M_) {
      const int b = i >> 10;         // / M_
      const int m = i & (M_ - 1);
      const int chunk = m >> 7;      // / CHUNK
      const int mi = m & (CHUNK - 1);
      const int pair = mi >> 1;
      const int sub = mi & 1;
      const float x = cxyz[3 * i + 0];
      const float y = cxyz[3 * i + 1];
      const float z = cxyz[3 * i + 2];
      const float w = x * x + y * y + z * z;
      float* pb = csoa + ((((size_t)b * NCHUNK + chunk) * (CHUNK / 2)) + pair) * 8 + sub;
      pb[0] = x; pb[2] = y; pb[4] = z; pb[6] = w;
      cpack[i] = make_float4(x, y, z, w);
    }
  } else {
    // ---- transpose role ----
    const int bid = blockIdx.x - 32;       // 0..2047
    const int m0 = (bid & 31) * 32;        // M/32 = 32
    const int c0 = ((bid >> 5) & 7) * 32;  // C/32 = 8
    const int b = bid >> 8;
    const float* fb = cf + (size_t)b * C_ * M_;
    float* ftb = fT + (size_t)b * M_ * C_;
#pragma unroll
    for (int j = 0; j < 32; j += 8)
      tile[ty + j][tx] = fb[(size_t)(c0 + ty + j) * M_ + (m0 + tx)];
    __syncthreads();
#pragma unroll
    for (int j = 0; j < 32; j += 8)
      ftb[(size_t)(m0 + ty + j) * C_ + (c0 + tx)] = tile[tx][ty + j];
  }
}

// ---------------------------------------------------------------------------
// Kernel 1: chunked top-4 -- R5 structure, AMPLIFIED x5.
// "+s"-laundered chunk base (re-loads each rep, s_load codegen preserved)
// + per-rep "v" value sink on A0..A3 (compute stays live) + single final
// store (byte-identical output). T_topk = this dispatch's dur / 5.
// ---------------------------------------------------------------------------
__global__ __launch_bounds__(TOPK_BLOCK) void topk_chunk_kernel(
    const float* __restrict__ xyz,   // [B, N, 3]
    const float* __restrict__ csoa,  // [B][NCHUNK][CHUNK/2][8]
    unsigned* __restrict__ cand)     // [B*N][NCHUNK]: 4 packed 8-bit indices
{
  const int b = blockIdx.z;
  const int chunk = blockIdx.y;
  const int n = blockIdx.x * TOPK_BLOCK + threadIdx.x;
  const size_t p = (size_t)b * N_ + n;

  unsigned long long cbo =
      (unsigned long long)((((size_t)b * NCHUNK + chunk) * (CHUNK / 2)) * 8);

  const float* xp = xyz + p * 3;
  const float x0 = xp[0], x1 = xp[1], x2 = xp[2];
  const float nx0 = -2.f * x0, nx1 = -2.f * x1, nx2 = -2.f * x2;
  const float x2p1 = fmaf(x0, x0, fmaf(x1, x1, fmaf(x2, x2, 1.0f)));

  float A0 = INFINITY, A1 = INFINITY, A2 = INFINITY, A3 = INFINITY;

  for (int rep = 0; rep < TOPK_REPS; ++rep) {
    // launder the chunk base offset: opaque SGPR value -> loads below
    // cannot be CSE'd with a previous rep's loads.
    asm volatile("" : "+s"(cbo));
    const float* __restrict__ cb = csoa + cbo;

    float a0 = INFINITY, a1 = INFINITY, a2 = INFINITY, a3 = INFINITY;
    float B0 = INFINITY, B1 = INFINITY, B2 = INFINITY, B3 = INFINITY;

#pragma unroll 8
    for (int i = 0; i < CHUNK / 2; ++i) {
      const float* pb = cb + i * 8;
      float tx = fmaf(nx0, pb[0], x2p1), ty = fmaf(nx0, pb[1], x2p1);
      tx = fmaf(nx1, pb[2], tx); ty = fmaf(nx1, pb[3], ty);
      tx = fmaf(nx2, pb[4], tx); ty = fmaf(nx2, pb[5], ty);
      tx += pb[6]; ty += pb[7];  // key = d^2 + 1 > 0
      const float kx = __uint_as_float((__float_as_uint(tx) & 0xFFFFFF80u) | (unsigned)(2 * i));
      const float ky = __uint_as_float((__float_as_uint(ty) & 0xFFFFFF80u) | (unsigned)(2 * i + 1));
      INSERT4(a, kx);
      INSERT4(B, ky);
    }
    INSERT4(a, B0);
    INSERT4(a, B1);
    INSERT4(a, B2);
    INSERT4(a, B3);

    // rule-17 value sink: keeps every rep's full compute DAG live without
    // a store (defeats DSE->DCE that ate R10's reps).
    asm volatile("" :: "v"(a0), "v"(a1), "v"(a2), "v"(a3));
    A0 = a0; A1 = a1; A2 = a2; A3 = a3;
  }

  const unsigned i0 = __float_as_uint(A0) & 127u;
  const unsigned i1 = __float_as_uint(A1) & 127u;
  const unsigned i2 = __float_as_uint(A2) & 127u;
  const unsigned i3 = __float_as_uint(A3) & 127u;
  cand[p * NCHUNK + chunk] = i0 | (i1 << 8) | (i2 << 16) | (i3 << 24);
}

// ---------------------------------------------------------------------------
// Kernel 2: merge 8x4 candidates -> exact global top-3 + weights. VERBATIM
// proven structure (f64 re-rank, stable strict-< insertion). 1x.
// ---------------------------------------------------------------------------
__global__ __launch_bounds__(256) void merge_kernel(
    const float* __restrict__ xyz,     // [B, N, 3]
    const float4* __restrict__ cpack,  // [B*M]
    const unsigned* __restrict__ cand, // [B*N][NCHUNK]
    int*   __restrict__ out_idx,       // [B*N, 3]
    float* __restrict__ out_w)         // [B*N, 3]
{
  const size_t p = (size_t)blockIdx.x * 256 + threadIdx.x;
  const int b = (int)(p >> 14);  // p / N_

  const float* xp = xyz + p * 3;
  const double x0d = (double)xp[0], x1d = (double)xp[1], x2d = (double)xp[2];
  const float4* __restrict__ cb = cpack + (size_t)b * M_;

  const uint4* cw4 = (const uint4*)(cand + p * NCHUNK);
  const uint4 ca = cw4[0], cb2 = cw4[1];
  unsigned words[NCHUNK] = {ca.x, ca.y, ca.z, ca.w, cb2.x, cb2.y, cb2.z, cb2.w};

  double D0 = 1e300, D1 = 1e300, D2 = 1e300;
  int I0 = 0, I1 = 0, I2 = 0;
#pragma unroll
  for (int ch = 0; ch < NCHUNK; ++ch) {
    const unsigned w = words[ch];
#pragma unroll
    for (int j = 0; j < KEEP; ++j) {
      const int m = ch * CHUNK + (int)((w >> (8 * j)) & 255u);
      const float4 c = cb[m];
      const double cx = (double)c.x, cy = (double)c.y, cz = (double)c.z;
      const double dot = x0d * cx + x1d * cy + x2d * cz;
      const double c2d = cx * cx + cy * cy + cz * cz;
      const double kd = c2d - 2.0 * dot;
      if (kd < D2) {
        if (kd < D1) {
          D2 = D1; I2 = I1;
          if (kd < D0) { D1 = D0; I1 = I0; D0 = kd; I0 = m; }
          else         { D1 = kd; I1 = m; }
        } else {
          D2 = kd; I2 = m;
        }
      }
    }
  }

  const double xx = x0d * x0d + x1d * x1d + x2d * x2d;
  const float d0 = sqrtf(fmaxf((float)(xx + D0), 0.0f));
  const float d1 = sqrtf(fmaxf((float)(xx + D1), 0.0f));
  const float d2 = sqrtf(fmaxf((float)(xx + D2), 0.0f));
  float w0 = 1.0f / fmaxf(d0, 1e-8f);
  float w1 = 1.0f / fmaxf(d1, 1e-8f);
  float w2 = 1.0f / fmaxf(d2, 1e-8f);
  const float wsum = w0 + w1 + w2;
  w0 /= wsum; w1 /= wsum; w2 /= wsum;

  const size_t o = p * 3;
  out_idx[o + 0] = I0; out_idx[o + 1] = I1; out_idx[o + 2] = I2;
  out_w[o + 0] = w0;   out_w[o + 1] = w1;   out_w[o + 2] = w2;
}

// ---------------------------------------------------------------------------
// Kernel 3: weighted feature gather -- R5 structure (batch<->XCD swizzle +
// nt stores), read-side AMPLIFIED x3: "+s"-laundered fT base (b scalar by
// construction) + per-rep "v" sink on the weighted sum; single nt store
// after the loop. T_gread ~ (dispatch dur - 20us write) / 3; FETCH_SIZE
// tells whether fT reads are L2-resident (small) or HBM (large).
// ---------------------------------------------------------------------------
__global__ __launch_bounds__(256) void gather_kernel(
    const float* __restrict__ fT,   // [B, M, C]
    const int*   __restrict__ idx,  // [B*N, 3]
    const float* __restrict__ w,    // [B*N, 3]
    float* __restrict__ out)        // [B, N, C]
{
  const int wid  = threadIdx.x >> 6;
  const int lane = threadIdx.x & 63;
  // batch<->XCD swizzle: 32768 groups of 4 points; 4096 groups per batch.
  const int b = (int)(blockIdx.x & 7);            // scalar by construction
  const int g = b * 4096 + (int)(blockIdx.x >> 3);
  const size_t p = (size_t)g * 4 + wid;           // global point id

  const size_t o = p * 3;
  const int i0 = idx[o + 0], i1 = idx[o + 1], i2 = idx[o + 2];
  const float w0 = w[o + 0], w1 = w[o + 1], w2 = w[o + 2];

  unsigned long long fo = (unsigned long long)b * (M_ * (C_ / 4));

  nfloat4 r;
  for (int rep = 0; rep < GATHER_REPS; ++rep) {
    asm volatile("" : "+s"(fo));  // opaque scalar base -> loads re-execute
    const float4* f4 = (const float4*)fT + fo;
    float4 a = f4[(size_t)i0 * (C_ / 4) + lane];
    float4 bb = f4[(size_t)i1 * (C_ / 4) + lane];
    float4 c = f4[(size_t)i2 * (C_ / 4) + lane];

    r.x = w0 * a.x + w1 * bb.x + w2 * c.x;
    r.y = w0 * a.y + w1 * bb.y + w2 * c.y;
    r.z = w0 * a.z + w1 * bb.z + w2 * c.z;
    r.w = w0 * a.w + w1 * bb.w + w2 * c.w;
    // rule-17 value sink: keeps each rep's loads + FLOPs live.
    asm volatile("" :: "v"(r.x), "v"(r.y), "v"(r.z), "v"(r.w));
  }

  __builtin_nontemporal_store(r, &((nfloat4*)out)[p * (C_ / 4) + lane]);
}

extern "C" void kernel_launch(void* const* d_in, const int* in_sizes, int n_in,
                              void* d_out, int out_size, void* d_ws, size_t ws_size,
                              hipStream_t stream) {
  const float* xyz  = (const float*)d_in[0];  // [B, N, 3]
  const float* cxyz = (const float*)d_in[1];  // [B, M, 3]
  const float* cf   = (const float*)d_in[2];  // [B, C, M]
  float* out = (float*)d_out;                 // [B, N, C]

  char* ws = (char*)d_ws;
  const size_t npts = (size_t)B_ * N_;

  int*    idxbuf = (int*)ws;                              // npts*3 ints
  float*  wbuf   = (float*)(ws + npts * 3 * sizeof(int)); // npts*3 floats
  size_t  off    = npts * 3 * 8;
  float4* cpack  = (float4*)(ws + off);                   // B*M float4 (128 KB)
  off += (size_t)B_ * M_ * sizeof(float4);
  float*  csoa   = (float*)(ws + off);                    // B*M*4 floats (128 KB)
  off += (size_t)B_ * M_ * 4 * sizeof(float);
  off = (off + 15) & ~(size_t)15;
  char*   region = ws + off;
  unsigned* cand = (unsigned*)region;  // npts*NCHUNK*4B = 4.2 MB
  size_t cand_bytes = (npts * (size_t)NCHUNK * 4 + 255) & ~(size_t)255;
  float* fT = (float*)(region + cand_bytes);  // B*M*C floats = 8 MB

  prep_kernel<<<dim3(32 + 2048), dim3(32, 8), 0, stream>>>(
      cxyz, cf, csoa, cpack, fT);
  topk_chunk_kernel<<<dim3(N_ / TOPK_BLOCK, NCHUNK, B_), TOPK_BLOCK, 0, stream>>>(
      xyz, csoa, cand);
  merge_kernel<<<(unsigned)(npts / 256), 256, 0, stream>>>(
      xyz, cpack, cand, idxbuf, wbuf);
  gather_kernel<<<(unsigned)(npts / 4), 256, 0, stream>>>(fT, idxbuf, wbuf, out);
}

// Round 12
// 84.665 us; speedup vs baseline: 2.9548x; 2.9548x over previous
//
#include <hip/hip_runtime.h>
#include <math.h>

// Problem constants (fixed by setup_inputs)
constexpr int B_ = 8;
constexpr int N_ = 16384;
constexpr int M_ = 1024;
constexpr int C_ = 256;
constexpr int NCHUNK = 8;
constexpr int CHUNK = M_ / NCHUNK;  // 128
constexpr int KEEP = 4;             // per-chunk survivors
constexpr int TOPK_BLOCK = 1024;    // 16 waves/block -> 2 blocks/CU -> 2 K$ streams

// R11 probe calibration (laundered x5 amplification, rocprof-visible):
//   T_topk ~= 41us of the 86.4us total, VALUBusy ~100%, FETCH 1.9MB,
//   VGPR 24 -> topk is pure VALU-issue-bound. Gather's marginal read cost
//   ~0 (cache-hot reps) -> gather ~ at its write floor. So R12 attacks
//   topk's instruction count: packed-fp32 (v_pk_fma_f32) for the distance
//   chain -- csoa's pair-interleaved layout makes each 64-bit s_load pair
//   exactly one packed operand. pk_fma rounds identically per lane ->
//   keys bit-identical -> output bit-identical.

// native vectors (clang ext_vector): float2 for packed-fp32 math, float4
// for __builtin_nontemporal_store (HIP's float4 class is rejected there).
typedef float f32x2 __attribute__((ext_vector_type(2)));
typedef float nfloat4 __attribute__((ext_vector_type(4)));

// 4-deep sorted-insert network on POSITIVE floats (P0<=P1<=P2<=P3 invariant).
// min + 3x v_med3_f32, all VOP3-legal.
#define INSERT4(P, u)                                              \
  {                                                                \
    const float o0 = P##0, o1 = P##1, o2 = P##2;                   \
    P##0 = fminf(o0, (u));                                         \
    P##1 = __builtin_amdgcn_fmed3f(o0, P##1, (u));                 \
    P##2 = __builtin_amdgcn_fmed3f(o1, P##2, (u));                 \
    P##3 = __builtin_amdgcn_fmed3f(o2, P##3, (u));                 \
  }

// ---------------------------------------------------------------------------
// Kernel 0 (fused prep): blocks [0,32) pack centroids; blocks [32, 32+2048)
// transpose centroid_f [B,C,M] -> fT [B,M,C] via 32x32 LDS tiles (+1 pad).
// ---------------------------------------------------------------------------
__global__ __launch_bounds__(256) void prep_kernel(
    const float* __restrict__ cxyz,  // [B, M, 3]
    const float* __restrict__ cf,    // [B, C, M]
    float* __restrict__ csoa,        // [B][NCHUNK][CHUNK/2][8]
    float4* __restrict__ cpack,      // [B*M]
    float* __restrict__ fT)          // [B, M, C]
{
  __shared__ float tile[32][33];
  const int tx = threadIdx.x;  // 0..31
  const int ty = threadIdx.y;  // 0..7
  if (blockIdx.x < 32) {
    // ---- pack role ----
    const int i = blockIdx.x * 256 + (ty * 32 + tx);  // global centroid id
    if (i < B_ * M_) {
      const int b = i >> 10;         // / M_
      const int m = i & (M_ - 1);
      const int chunk = m >> 7;      // / CHUNK
      const int mi = m & (CHUNK - 1);
      const int pair = mi >> 1;
      const int sub = mi & 1;
      const float x = cxyz[3 * i + 0];
      const float y = cxyz[3 * i + 1];
      const float z = cxyz[3 * i + 2];
      const float w = x * x + y * y + z * z;
      float* pb = csoa + ((((size_t)b * NCHUNK + chunk) * (CHUNK / 2)) + pair) * 8 + sub;
      pb[0] = x; pb[2] = y; pb[4] = z; pb[6] = w;
      cpack[i] = make_float4(x, y, z, w);
    }
  } else {
    // ---- transpose role ----
    const int bid = blockIdx.x - 32;       // 0..2047
    const int m0 = (bid & 31) * 32;        // M/32 = 32
    const int c0 = ((bid >> 5) & 7) * 32;  // C/32 = 8
    const int b = bid >> 8;
    const float* fb = cf + (size_t)b * C_ * M_;
    float* ftb = fT + (size_t)b * M_ * C_;
#pragma unroll
    for (int j = 0; j < 32; j += 8)
      tile[ty + j][tx] = fb[(size_t)(c0 + ty + j) * M_ + (m0 + tx)];
    __syncthreads();
#pragma unroll
    for (int j = 0; j < 32; j += 8)
      ftb[(size_t)(m0 + ty + j) * C_ + (c0 + tx)] = tile[tx][ty + j];
  }
}

// ---------------------------------------------------------------------------
// Kernel 1: chunked top-4 -- R5 structure with PACKED-FP32 distance math.
// Per iteration (2 keys): 4 pk ops (3 pk_fma + 1 pk_add) replace 8 scalar
// fma/add; mantissa-pack written in (x&M)|(i&~M) form so the backend can
// emit v_bfi_b32. INSERT4 chains unchanged (min/med3 have no pk form;
// KEEP=4 margin retained). pk_fma == fma per lane -> keys bit-identical.
// DO NOT fuse other roles into this kernel (R1/R2 lesson: union-kernel
// regalloc broke its 64-VGPR/8-wave contract, 167-183us).
// ---------------------------------------------------------------------------
__global__ __launch_bounds__(TOPK_BLOCK) void topk_chunk_kernel(
    const float* __restrict__ xyz,   // [B, N, 3]
    const float* __restrict__ csoa,  // [B][NCHUNK][CHUNK/2][8]
    unsigned* __restrict__ cand)     // [B*N][NCHUNK]: 4 packed 8-bit indices
{
  const int b = blockIdx.z;
  const int chunk = blockIdx.y;
  const int n = blockIdx.x * TOPK_BLOCK + threadIdx.x;
  const size_t p = (size_t)b * N_ + n;

  const f32x2* __restrict__ cb2 = (const f32x2*)(
      csoa + (((size_t)b * NCHUNK + chunk) * (CHUNK / 2)) * 8);

  const float* xp = xyz + p * 3;
  const float x0 = xp[0], x1 = xp[1], x2 = xp[2];
  const float x2p1 = fmaf(x0, x0, fmaf(x1, x1, fmaf(x2, x2, 1.0f)));
  const f32x2 nx0_2 = {-2.f * x0, -2.f * x0};
  const f32x2 nx1_2 = {-2.f * x1, -2.f * x1};
  const f32x2 nx2_2 = {-2.f * x2, -2.f * x2};
  const f32x2 x2p1_2 = {x2p1, x2p1};

  float A0 = INFINITY, A1 = INFINITY, A2 = INFINITY, A3 = INFINITY;
  float B0 = INFINITY, B1 = INFINITY, B2 = INFINITY, B3 = INFINITY;

#pragma unroll 8
  for (int i = 0; i < CHUNK / 2; ++i) {
    // {x0,x1},{y0,y1},{z0,z1},{w0,w1} -- one packed operand per 8B pair
    const f32x2 cx = cb2[i * 4 + 0];
    const f32x2 cy = cb2[i * 4 + 1];
    const f32x2 cz = cb2[i * 4 + 2];
    const f32x2 cw = cb2[i * 4 + 3];

    f32x2 t = __builtin_elementwise_fma(nx0_2, cx, x2p1_2);
    t = __builtin_elementwise_fma(nx1_2, cy, t);
    t = __builtin_elementwise_fma(nx2_2, cz, t);
    t = t + cw;  // key = d^2 + 1 > 0

    // pack 7-bit local index into low mantissa bits (bfi-matchable form)
    const unsigned ie = (unsigned)(2 * i), io = (unsigned)(2 * i + 1);
    const float kx = __uint_as_float(
        (__float_as_uint(t.x) & 0xFFFFFF80u) | (ie & 0x0000007Fu));
    const float ky = __uint_as_float(
        (__float_as_uint(t.y) & 0xFFFFFF80u) | (io & 0x0000007Fu));
    INSERT4(A, kx);
    INSERT4(B, ky);
  }
  // fold chain B into chain A (exact running-inserts)
  INSERT4(A, B0);
  INSERT4(A, B1);
  INSERT4(A, B2);
  INSERT4(A, B3);

  const unsigned i0 = __float_as_uint(A0) & 127u;
  const unsigned i1 = __float_as_uint(A1) & 127u;
  const unsigned i2 = __float_as_uint(A2) & 127u;
  const unsigned i3 = __float_as_uint(A3) & 127u;
  cand[p * NCHUNK + chunk] = i0 | (i1 << 8) | (i2 << 16) | (i3 << 24);
}

// ---------------------------------------------------------------------------
// Kernel 2: merge 8x4 candidates -> exact global top-3 + weights. VERBATIM
// proven structure (f64 re-rank, stable strict-< insertion). Standalone so
// its ~90-VGPR f64 path sets only its own occupancy (R4 lesson).
// ---------------------------------------------------------------------------
__global__ __launch_bounds__(256) void merge_kernel(
    const float* __restrict__ xyz,     // [B, N, 3]
    const float4* __restrict__ cpack,  // [B*M]
    const unsigned* __restrict__ cand, // [B*N][NCHUNK]
    int*   __restrict__ out_idx,       // [B*N, 3]
    float* __restrict__ out_w)         // [B*N, 3]
{
  const size_t p = (size_t)blockIdx.x * 256 + threadIdx.x;
  const int b = (int)(p >> 14);  // p / N_

  const float* xp = xyz + p * 3;
  const double x0d = (double)xp[0], x1d = (double)xp[1], x2d = (double)xp[2];
  const float4* __restrict__ cb = cpack + (size_t)b * M_;

  const uint4* cw4 = (const uint4*)(cand + p * NCHUNK);
  const uint4 ca = cw4[0], cb2 = cw4[1];
  unsigned words[NCHUNK] = {ca.x, ca.y, ca.z, ca.w, cb2.x, cb2.y, cb2.z, cb2.w};

  double D0 = 1e300, D1 = 1e300, D2 = 1e300;
  int I0 = 0, I1 = 0, I2 = 0;
#pragma unroll
  for (int ch = 0; ch < NCHUNK; ++ch) {
    const unsigned w = words[ch];
#pragma unroll
    for (int j = 0; j < KEEP; ++j) {
      const int m = ch * CHUNK + (int)((w >> (8 * j)) & 255u);
      const float4 c = cb[m];
      const double cx = (double)c.x, cy = (double)c.y, cz = (double)c.z;
      const double dot = x0d * cx + x1d * cy + x2d * cz;
      const double c2d = cx * cx + cy * cy + cz * cz;
      const double kd = c2d - 2.0 * dot;
      if (kd < D2) {
        if (kd < D1) {
          D2 = D1; I2 = I1;
          if (kd < D0) { D1 = D0; I1 = I0; D0 = kd; I0 = m; }
          else         { D1 = kd; I1 = m; }
        } else {
          D2 = kd; I2 = m;
        }
      }
    }
  }

  const double xx = x0d * x0d + x1d * x1d + x2d * x2d;
  const float d0 = sqrtf(fmaxf((float)(xx + D0), 0.0f));
  const float d1 = sqrtf(fmaxf((float)(xx + D1), 0.0f));
  const float d2 = sqrtf(fmaxf((float)(xx + D2), 0.0f));
  float w0 = 1.0f / fmaxf(d0, 1e-8f);
  float w1 = 1.0f / fmaxf(d1, 1e-8f);
  float w2 = 1.0f / fmaxf(d2, 1e-8f);
  const float wsum = w0 + w1 + w2;
  w0 /= wsum; w1 /= wsum; w2 /= wsum;

  const size_t o = p * 3;
  out_idx[o + 0] = I0; out_idx[o + 1] = I1; out_idx[o + 2] = I2;
  out_w[o + 0] = w0;   out_w[o + 1] = w1;   out_w[o + 2] = w2;
}

// ---------------------------------------------------------------------------
// Kernel 3: weighted feature gather -- VERBATIM R5 (batch<->XCD swizzle +
// non-temporal output stores). R11 showed marginal read cost ~0 -> this
// kernel is near its write floor; leave it alone.
// ---------------------------------------------------------------------------
__global__ __launch_bounds__(256) void gather_kernel(
    const float* __restrict__ fT,   // [B, M, C]
    const int*   __restrict__ idx,  // [B*N, 3]
    const float* __restrict__ w,    // [B*N, 3]
    float* __restrict__ out)        // [B, N, C]
{
  const int wid  = threadIdx.x >> 6;
  const int lane = threadIdx.x & 63;
  // batch<->XCD swizzle: 32768 groups of 4 points; 4096 groups per batch.
  const int g = (blockIdx.x & 7) * 4096 + (blockIdx.x >> 3);
  const size_t p = (size_t)g * 4 + wid;  // global point id
  const int b = (int)(p >> 14);          // p / N_  (== blockIdx.x & 7)

  const size_t o = p * 3;
  const int i0 = idx[o + 0], i1 = idx[o + 1], i2 = idx[o + 2];
  const float w0 = w[o + 0], w1 = w[o + 1], w2 = w[o + 2];

  const float4* f4 = (const float4*)(fT + (size_t)b * M_ * C_);
  float4 a = f4[(size_t)i0 * (C_ / 4) + lane];
  float4 bb = f4[(size_t)i1 * (C_ / 4) + lane];
  float4 c = f4[(size_t)i2 * (C_ / 4) + lane];

  nfloat4 r;
  r.x = w0 * a.x + w1 * bb.x + w2 * c.x;
  r.y = w0 * a.y + w1 * bb.y + w2 * c.y;
  r.z = w0 * a.z + w1 * bb.z + w2 * c.z;
  r.w = w0 * a.w + w1 * bb.w + w2 * c.w;

  __builtin_nontemporal_store(r, &((nfloat4*)out)[p * (C_ / 4) + lane]);
}

extern "C" void kernel_launch(void* const* d_in, const int* in_sizes, int n_in,
                              void* d_out, int out_size, void* d_ws, size_t ws_size,
                              hipStream_t stream) {
  const float* xyz  = (const float*)d_in[0];  // [B, N, 3]
  const float* cxyz = (const float*)d_in[1];  // [B, M, 3]
  const float* cf   = (const float*)d_in[2];  // [B, C, M]
  float* out = (float*)d_out;                 // [B, N, C]

  char* ws = (char*)d_ws;
  const size_t npts = (size_t)B_ * N_;

  int*    idxbuf = (int*)ws;                              // npts*3 ints
  float*  wbuf   = (float*)(ws + npts * 3 * sizeof(int)); // npts*3 floats
  size_t  off    = npts * 3 * 8;
  float4* cpack  = (float4*)(ws + off);                   // B*M float4 (128 KB)
  off += (size_t)B_ * M_ * sizeof(float4);
  float*  csoa   = (float*)(ws + off);                    // B*M*4 floats (128 KB)
  off += (size_t)B_ * M_ * 4 * sizeof(float);
  off = (off + 15) & ~(size_t)15;
  char*   region = ws + off;
  unsigned* cand = (unsigned*)region;  // npts*NCHUNK*4B = 4.2 MB
  size_t cand_bytes = (npts * (size_t)NCHUNK * 4 + 255) & ~(size_t)255;
  float* fT = (float*)(region + cand_bytes);  // B*M*C floats = 8 MB

  prep_kernel<<<dim3(32 + 2048), dim3(32, 8), 0, stream>>>(
      cxyz, cf, csoa, cpack, fT);
  topk_chunk_kernel<<<dim3(N_ / TOPK_BLOCK, NCHUNK, B_), TOPK_BLOCK, 0, stream>>>(
      xyz, csoa, cand);
  merge_kernel<<<(unsigned)(npts / 256), 256, 0, stream>>>(
      xyz, cpack, cand, idxbuf, wbuf);
  gather_kernel<<<(unsigned)(npts / 4), 256, 0, stream>>>(fT, idxbuf, wbuf, out);
}

// Round 13
// 82.412 us; speedup vs baseline: 3.0355x; 1.0273x over previous
//
#include <hip/hip_runtime.h>
#include <math.h>

// Problem constants (fixed by setup_inputs)
constexpr int B_ = 8;
constexpr int N_ = 16384;
constexpr int M_ = 1024;
constexpr int C_ = 256;
constexpr int NCHUNK = 8;
constexpr int CHUNK = M_ / NCHUNK;  // 128
constexpr int KEEP = 4;             // per-chunk survivors
constexpr int TOPK_BLOCK = 1024;    // 16 waves/block -> 2 blocks/CU -> 2 K$ streams

// Calibration (R11 probe): T_topk ~41us @ VALUBusy~100% -> topk is pure
// VALU-issue-bound; gather ~write-floor; prep+merge+gaps ~ floors.
// R12 lesson: v_pk_*_f32 double-pumps the SIMD-32 FP32 ALU (peak 157TF is
// defined by scalar fma) -> pk is issue-equivalent to 2 scalar ops; only
// REAL op removal buys time. R13 removes 2 equiv-ops/pair:
//   (1) start distance accum from cw: key = |c|^2 - 2x.c (3 pk_fma, no
//       pk_add). Negative keys are fine for min/med3 ordering and merge's
//       f64 kd is already this exact expression; only same-quantum
//       boundary ties at chunk rank-4 flip index direction (P~1e-9 class).
//   (2) v_bfi_b32 (forced via inline asm) for the mantissa-index pack:
//       1 op/key instead of AND+OR.

// native vectors (clang ext_vector): float2 for packed-fp32 math, float4
// for __builtin_nontemporal_store (HIP's float4 class is rejected there).
typedef float f32x2 __attribute__((ext_vector_type(2)));
typedef float nfloat4 __attribute__((ext_vector_type(4)));

// 4-deep sorted-insert network (P0<=P1<=P2<=P3 invariant); valid for any
// non-NaN floats incl. negatives. min + 3x v_med3_f32, all VOP3-legal.
#define INSERT4(P, u)                                              \
  {                                                                \
    const float o0 = P##0, o1 = P##1, o2 = P##2;                   \
    P##0 = fminf(o0, (u));                                         \
    P##1 = __builtin_amdgcn_fmed3f(o0, P##1, (u));                 \
    P##2 = __builtin_amdgcn_fmed3f(o1, P##2, (u));                 \
    P##3 = __builtin_amdgcn_fmed3f(o2, P##3, (u));                 \
  }

// ---------------------------------------------------------------------------
// Kernel 0 (fused prep): blocks [0,32) pack centroids; blocks [32, 32+2048)
// transpose centroid_f [B,C,M] -> fT [B,M,C] via 32x32 LDS tiles (+1 pad).
// ---------------------------------------------------------------------------
__global__ __launch_bounds__(256) void prep_kernel(
    const float* __restrict__ cxyz,  // [B, M, 3]
    const float* __restrict__ cf,    // [B, C, M]
    float* __restrict__ csoa,        // [B][NCHUNK][CHUNK/2][8]
    float4* __restrict__ cpack,      // [B*M]
    float* __restrict__ fT)          // [B, M, C]
{
  __shared__ float tile[32][33];
  const int tx = threadIdx.x;  // 0..31
  const int ty = threadIdx.y;  // 0..7
  if (blockIdx.x < 32) {
    // ---- pack role ----
    const int i = blockIdx.x * 256 + (ty * 32 + tx);  // global centroid id
    if (i < B_ * M_) {
      const int b = i >> 10;         // / M_
      const int m = i & (M_ - 1);
      const int chunk = m >> 7;      // / CHUNK
      const int mi = m & (CHUNK - 1);
      const int pair = mi >> 1;
      const int sub = mi & 1;
      const float x = cxyz[3 * i + 0];
      const float y = cxyz[3 * i + 1];
      const float z = cxyz[3 * i + 2];
      const float w = x * x + y * y + z * z;
      float* pb = csoa + ((((size_t)b * NCHUNK + chunk) * (CHUNK / 2)) + pair) * 8 + sub;
      pb[0] = x; pb[2] = y; pb[4] = z; pb[6] = w;
      cpack[i] = make_float4(x, y, z, w);
    }
  } else {
    // ---- transpose role ----
    const int bid = blockIdx.x - 32;       // 0..2047
    const int m0 = (bid & 31) * 32;        // M/32 = 32
    const int c0 = ((bid >> 5) & 7) * 32;  // C/32 = 8
    const int b = bid >> 8;
    const float* fb = cf + (size_t)b * C_ * M_;
    float* ftb = fT + (size_t)b * M_ * C_;
#pragma unroll
    for (int j = 0; j < 32; j += 8)
      tile[ty + j][tx] = fb[(size_t)(c0 + ty + j) * M_ + (m0 + tx)];
    __syncthreads();
#pragma unroll
    for (int j = 0; j < 32; j += 8)
      ftb[(size_t)(m0 + ty + j) * C_ + (c0 + tx)] = tile[tx][ty + j];
  }
}

// ---------------------------------------------------------------------------
// Kernel 1: chunked top-4 -- R12 structure minus 2 equiv-ops/pair:
//   key = |c|^2 - 2x.c  (3 pk_fma, accumulate from cw; no +|p|^2 bias)
//   index pack via v_bfi_b32 (1 op/key; mask in VGPR, index in SGPR)
// Per iter (2 keys): 3 pk + 2 bfi + 8 min/med3 = 16 equiv (was 20).
// merge's f64 kd is the same expression -> ranking semantics unchanged.
// DO NOT fuse other roles into this kernel (R1/R2 lesson).
// ---------------------------------------------------------------------------
__global__ __launch_bounds__(TOPK_BLOCK) void topk_chunk_kernel(
    const float* __restrict__ xyz,   // [B, N, 3]
    const float* __restrict__ csoa,  // [B][NCHUNK][CHUNK/2][8]
    unsigned* __restrict__ cand)     // [B*N][NCHUNK]: 4 packed 8-bit indices
{
  const int b = blockIdx.z;
  const int chunk = blockIdx.y;
  const int n = blockIdx.x * TOPK_BLOCK + threadIdx.x;
  const size_t p = (size_t)b * N_ + n;

  const f32x2* __restrict__ cb2 = (const f32x2*)(
      csoa + (((size_t)b * NCHUNK + chunk) * (CHUNK / 2)) * 8);

  const float* xp = xyz + p * 3;
  const float x0 = xp[0], x1 = xp[1], x2 = xp[2];
  const f32x2 nx0_2 = {-2.f * x0, -2.f * x0};
  const f32x2 nx1_2 = {-2.f * x1, -2.f * x1};
  const f32x2 nx2_2 = {-2.f * x2, -2.f * x2};
  unsigned maskv = 0xFFFFFF80u;  // "v"-constrained -> hoisted VGPR constant

  float A0 = INFINITY, A1 = INFINITY, A2 = INFINITY, A3 = INFINITY;
  float B0 = INFINITY, B1 = INFINITY, B2 = INFINITY, B3 = INFINITY;

#pragma unroll 8
  for (int i = 0; i < CHUNK / 2; ++i) {
    // {x0,x1},{y0,y1},{z0,z1},{w0,w1} -- one packed operand per 8B pair
    const f32x2 cx = cb2[i * 4 + 0];
    const f32x2 cy = cb2[i * 4 + 1];
    const f32x2 cz = cb2[i * 4 + 2];
    const f32x2 cw = cb2[i * 4 + 3];

    // key = |c|^2 - 2 x.c  (3 pk_fma; rank-equivalent to d^2 per point)
    f32x2 t = __builtin_elementwise_fma(nx0_2, cx, cw);
    t = __builtin_elementwise_fma(nx1_2, cy, t);
    t = __builtin_elementwise_fma(nx2_2, cz, t);

    // pack 7-bit local index into low mantissa bits: one v_bfi_b32 per key
    // (S0=mask VGPR, S1=key VGPR, S2=index SGPR -> 1 SGPR operand, legal).
    unsigned kxu, kyu;
    asm("v_bfi_b32 %0, %1, %2, %3"
        : "=v"(kxu)
        : "v"(maskv), "v"(__float_as_uint(t.x)), "s"((unsigned)(2 * i)));
    asm("v_bfi_b32 %0, %1, %2, %3"
        : "=v"(kyu)
        : "v"(maskv), "v"(__float_as_uint(t.y)), "s"((unsigned)(2 * i + 1)));
    const float kx = __uint_as_float(kxu);
    const float ky = __uint_as_float(kyu);
    INSERT4(A, kx);
    INSERT4(B, ky);
  }
  // fold chain B into chain A (exact running-inserts)
  INSERT4(A, B0);
  INSERT4(A, B1);
  INSERT4(A, B2);
  INSERT4(A, B3);

  const unsigned i0 = __float_as_uint(A0) & 127u;
  const unsigned i1 = __float_as_uint(A1) & 127u;
  const unsigned i2 = __float_as_uint(A2) & 127u;
  const unsigned i3 = __float_as_uint(A3) & 127u;
  cand[p * NCHUNK + chunk] = i0 | (i1 << 8) | (i2 << 16) | (i3 << 24);
}

// ---------------------------------------------------------------------------
// Kernel 2: merge 8x4 candidates -> exact global top-3 + weights. VERBATIM
// proven structure (f64 re-rank kd = |c|^2 - 2x.c, stable strict-<
// insertion -- same expression the quantized keys now rank by).
// ---------------------------------------------------------------------------
__global__ __launch_bounds__(256) void merge_kernel(
    const float* __restrict__ xyz,     // [B, N, 3]
    const float4* __restrict__ cpack,  // [B*M]
    const unsigned* __restrict__ cand, // [B*N][NCHUNK]
    int*   __restrict__ out_idx,       // [B*N, 3]
    float* __restrict__ out_w)         // [B*N, 3]
{
  const size_t p = (size_t)blockIdx.x * 256 + threadIdx.x;
  const int b = (int)(p >> 14);  // p / N_

  const float* xp = xyz + p * 3;
  const double x0d = (double)xp[0], x1d = (double)xp[1], x2d = (double)xp[2];
  const float4* __restrict__ cb = cpack + (size_t)b * M_;

  const uint4* cw4 = (const uint4*)(cand + p * NCHUNK);
  const uint4 ca = cw4[0], cb2 = cw4[1];
  unsigned words[NCHUNK] = {ca.x, ca.y, ca.z, ca.w, cb2.x, cb2.y, cb2.z, cb2.w};

  double D0 = 1e300, D1 = 1e300, D2 = 1e300;
  int I0 = 0, I1 = 0, I2 = 0;
#pragma unroll
  for (int ch = 0; ch < NCHUNK; ++ch) {
    const unsigned w = words[ch];
#pragma unroll
    for (int j = 0; j < KEEP; ++j) {
      const int m = ch * CHUNK + (int)((w >> (8 * j)) & 255u);
      const float4 c = cb[m];
      const double cx = (double)c.x, cy = (double)c.y, cz = (double)c.z;
      const double dot = x0d * cx + x1d * cy + x2d * cz;
      const double c2d = cx * cx + cy * cy + cz * cz;
      const double kd = c2d - 2.0 * dot;
      if (kd < D2) {
        if (kd < D1) {
          D2 = D1; I2 = I1;
          if (kd < D0) { D1 = D0; I1 = I0; D0 = kd; I0 = m; }
          else         { D1 = kd; I1 = m; }
        } else {
          D2 = kd; I2 = m;
        }
      }
    }
  }

  const double xx = x0d * x0d + x1d * x1d + x2d * x2d;
  const float d0 = sqrtf(fmaxf((float)(xx + D0), 0.0f));
  const float d1 = sqrtf(fmaxf((float)(xx + D1), 0.0f));
  const float d2 = sqrtf(fmaxf((float)(xx + D2), 0.0f));
  float w0 = 1.0f / fmaxf(d0, 1e-8f);
  float w1 = 1.0f / fmaxf(d1, 1e-8f);
  float w2 = 1.0f / fmaxf(d2, 1e-8f);
  const float wsum = w0 + w1 + w2;
  w0 /= wsum; w1 /= wsum; w2 /= wsum;

  const size_t o = p * 3;
  out_idx[o + 0] = I0; out_idx[o + 1] = I1; out_idx[o + 2] = I2;
  out_w[o + 0] = w0;   out_w[o + 1] = w1;   out_w[o + 2] = w2;
}

// ---------------------------------------------------------------------------
// Kernel 3: weighted feature gather -- VERBATIM R5/R12 (batch<->XCD swizzle
// + non-temporal output stores). R11: marginal read cost ~0 -> near its
// write floor; leave it alone.
// ---------------------------------------------------------------------------
__global__ __launch_bounds__(256) void gather_kernel(
    const float* __restrict__ fT,   // [B, M, C]
    const int*   __restrict__ idx,  // [B*N, 3]
    const float* __restrict__ w,    // [B*N, 3]
    float* __restrict__ out)        // [B, N, C]
{
  const int wid  = threadIdx.x >> 6;
  const int lane = threadIdx.x & 63;
  // batch<->XCD swizzle: 32768 groups of 4 points; 4096 groups per batch.
  const int g = (blockIdx.x & 7) * 4096 + (blockIdx.x >> 3);
  const size_t p = (size_t)g * 4 + wid;  // global point id
  const int b = (int)(p >> 14);          // p / N_  (== blockIdx.x & 7)

  const size_t o = p * 3;
  const int i0 = idx[o + 0], i1 = idx[o + 1], i2 = idx[o + 2];
  const float w0 = w[o + 0], w1 = w[o + 1], w2 = w[o + 2];

  const float4* f4 = (const float4*)(fT + (size_t)b * M_ * C_);
  float4 a = f4[(size_t)i0 * (C_ / 4) + lane];
  float4 bb = f4[(size_t)i1 * (C_ / 4) + lane];
  float4 c = f4[(size_t)i2 * (C_ / 4) + lane];

  nfloat4 r;
  r.x = w0 * a.x + w1 * bb.x + w2 * c.x;
  r.y = w0 * a.y + w1 * bb.y + w2 * c.y;
  r.z = w0 * a.z + w1 * bb.z + w2 * c.z;
  r.w = w0 * a.w + w1 * bb.w + w2 * c.w;

  __builtin_nontemporal_store(r, &((nfloat4*)out)[p * (C_ / 4) + lane]);
}

extern "C" void kernel_launch(void* const* d_in, const int* in_sizes, int n_in,
                              void* d_out, int out_size, void* d_ws, size_t ws_size,
                              hipStream_t stream) {
  const float* xyz  = (const float*)d_in[0];  // [B, N, 3]
  const float* cxyz = (const float*)d_in[1];  // [B, M, 3]
  const float* cf   = (const float*)d_in[2];  // [B, C, M]
  float* out = (float*)d_out;                 // [B, N, C]

  char* ws = (char*)d_ws;
  const size_t npts = (size_t)B_ * N_;

  int*    idxbuf = (int*)ws;                              // npts*3 ints
  float*  wbuf   = (float*)(ws + npts * 3 * sizeof(int)); // npts*3 floats
  size_t  off    = npts * 3 * 8;
  float4* cpack  = (float4*)(ws + off);                   // B*M float4 (128 KB)
  off += (size_t)B_ * M_ * sizeof(float4);
  float*  csoa   = (float*)(ws + off);                    // B*M*4 floats (128 KB)
  off += (size_t)B_ * M_ * 4 * sizeof(float);
  off = (off + 15) & ~(size_t)15;
  char*   region = ws + off;
  unsigned* cand = (unsigned*)region;  // npts*NCHUNK*4B = 4.2 MB
  size_t cand_bytes = (npts * (size_t)NCHUNK * 4 + 255) & ~(size_t)255;
  float* fT = (float*)(region + cand_bytes);  // B*M*C floats = 8 MB

  prep_kernel<<<dim3(32 + 2048), dim3(32, 8), 0, stream>>>(
      cxyz, cf, csoa, cpack, fT);
  topk_chunk_kernel<<<dim3(N_ / TOPK_BLOCK, NCHUNK, B_), TOPK_BLOCK, 0, stream>>>(
      xyz, csoa, cand);
  merge_kernel<<<(unsigned)(npts / 256), 256, 0, stream>>>(
      xyz, cpack, cand, idxbuf, wbuf);
  gather_kernel<<<(unsigned)(npts / 4), 256, 0, stream>>>(fT, idxbuf, wbuf, out);
}